// Round 2
// baseline (181.269 us; speedup 1.0000x reference)
//
#include <hip/hip_runtime.h>
#include <hip/hip_bf16.h>
#include <stdint.h>

// GraphSAGE layer fused pipeline for MI355X (gfx950), round 5.
// memset(deg) | k_prep(cvt+hist+rank+Wcvt) | k_scan1 | k_scan2b | k_fill | k_main
// R4: k_main barrier-free (Mt wave-private), weights from global, LDS 9.2KB.
// R5: __launch_bounds__(256,6) — R4 measured VGPR=52 (combined ~84 with acc),
//     so bound-4 was the residency cap; bound-6 fits the same allocation with
//     +50% resident waves for the latency-bound gather. No other changes.

typedef __bf16 bf16x8 __attribute__((ext_vector_type(8)));
typedef float f32x4 __attribute__((ext_vector_type(4)));

__device__ __forceinline__ unsigned short f2bf(float f) {
  unsigned int u = __float_as_uint(f);
  u += 0x7FFFu + ((u >> 16) & 1u);   // RNE
  return (unsigned short)(u >> 16);
}

// ---- fused prep: x->bf16, degree histogram + per-edge rank, W^T -> bf16 ----
__global__ void k_prep(const float* __restrict__ x, unsigned short* __restrict__ xb,
                       int total4,
                       const int* __restrict__ dst, int* __restrict__ deg,
                       int* __restrict__ rank, int e,
                       const float* __restrict__ W_fc, unsigned short* __restrict__ WfcT_g,
                       const float* __restrict__ W_res, unsigned short* __restrict__ WresT_g) {
  int i = blockIdx.x * 256 + threadIdx.x;
  if (i < total4) {
    const float4 v = ((const float4*)x)[i];
    ushort4 o;
    o.x = f2bf(v.x); o.y = f2bf(v.y); o.z = f2bf(v.z); o.w = f2bf(v.w);
    ((ushort4*)xb)[i] = o;
  }
  if (i < e) rank[i] = atomicAdd(&deg[dst[i]], 1);
  if (i < 64 * 128) {              // WfcT_g[nc*128+k] = W_fc[k*64+nc]
    int nc = i >> 7, k = i & 127;
    WfcT_g[i] = f2bf(W_fc[k * 64 + nc]);
  }
  if (i < 64 * 64) {               // WresT_g[nc*64+k] = W_res[k*64+nc]
    int nc = i >> 6, k = i & 63;
    WresT_g[i] = f2bf(W_res[k * 64 + nc]);
  }
}

// ---- scan step 1: per-block exclusive scan of deg -> offsets, block sums ----
__global__ void k_scan1(const int* __restrict__ deg, int* __restrict__ offsets,
                        int* __restrict__ blksum, int n) {
  __shared__ int sc[256];
  int t = threadIdx.x;
  int i = blockIdx.x * 256 + t;
  int d = (i < n) ? deg[i] : 0;
  sc[t] = d;
  __syncthreads();
  for (int off = 1; off < 256; off <<= 1) {
    int v = (t >= off) ? sc[t - off] : 0;
    __syncthreads();
    sc[t] += v;
    __syncthreads();
  }
  if (i < n) offsets[i] = sc[t] - d;
  if (t == 255) blksum[blockIdx.x] = sc[255];
}

// ---- scan step 2: each block redundantly reduces blksum[0..bid) and adds ----
__global__ void k_scan2b(int* __restrict__ offsets, const int* __restrict__ blksum,
                         int n, int e) {
  const int bid = blockIdx.x, t = threadIdx.x;
  int v = 0;
  for (int j = t; j < bid; j += 256) v += blksum[j];
  v += __shfl_xor(v, 32); v += __shfl_xor(v, 16); v += __shfl_xor(v, 8);
  v += __shfl_xor(v, 4);  v += __shfl_xor(v, 2);  v += __shfl_xor(v, 1);
  __shared__ int red[4];
  if ((t & 63) == 0) red[t >> 6] = v;
  __syncthreads();
  int pre = red[0] + red[1] + red[2] + red[3];
  int i = bid * 256 + t;
  if (i < n) offsets[i] += pre;
  if (bid == (int)gridDim.x - 1 && t == 0) offsets[n] = e;
}

// ---- CSR fill: atomic-free, 4 edges per thread for ILP ----
__global__ void k_fill(const int* __restrict__ src, const int* __restrict__ dst,
                       const int* __restrict__ offsets, const int* __restrict__ rank,
                       int* __restrict__ csr, int e) {
  int i4 = (blockIdx.x * 256 + threadIdx.x) * 4;
  if (i4 + 3 < e) {
    const int4 d = *(const int4*)(dst + i4);
    const int4 r = *(const int4*)(rank + i4);
    const int4 s = *(const int4*)(src + i4);
    int p0 = offsets[d.x], p1 = offsets[d.y], p2 = offsets[d.z], p3 = offsets[d.w];
    csr[p0 + r.x] = s.x;
    csr[p1 + r.y] = s.y;
    csr[p2 + r.z] = s.z;
    csr[p3 + r.w] = s.w;
  } else {
    for (int i = i4; i < e; ++i) csr[offsets[dst[i]] + rank[i]] = src[i];
  }
}

// ---- fused main: 64-node tile per block, 4 waves, NO block barrier ----
// Mt rows for wave w's MFMA A-fragments (rows 16w..16w+15) are written
// exclusively by wave w's own gather threads (nd = tid>>2), so the
// gather->MFMA handoff is wave-private: no __syncthreads needed.
#define XT_S 72

__global__ __launch_bounds__(256, 6) void k_main(
    const unsigned short* __restrict__ xb,
    const int* __restrict__ offsets, const int* __restrict__ csr,
    const unsigned short* __restrict__ WfcT_g,
    const unsigned short* __restrict__ WresT_g,
    const float* __restrict__ b_fc, const float* __restrict__ b_res,
    float* __restrict__ out, int n) {
  __shared__ unsigned short Mt[64 * XT_S];     // mean tile, bf16 (9.2 KB)

  const int tid = threadIdx.x;
  const int tile0 = blockIdx.x * 64;

  // ---- gather: thread -> (node nd, 16-feature chunk c); two independent
  // edge chains per thread, each with dist-1 row / dist-2 index prefetch.
  {
    const int nd = tid >> 2;
    const int c = tid & 3;
    const int node = tile0 + nd;
    float s[16], sb[16];
#pragma unroll
    for (int k = 0; k < 16; ++k) { s[k] = 0.f; sb[k] = 0.f; }
    int dg = 0;
    if (node < n) {
      const int o0 = offsets[node];
      const int o1 = offsets[node + 1];
      dg = o1 - o0;
      if (dg > 0) {
        const int hb = dg >> 1;          // chain B length
        const int ha = dg - hb;          // chain A length (>= hb)
        const int lastA = o0 + ha - 1;
        const int lastE = o1 - 1;
        const unsigned short* __restrict__ xbp = xb;
        // edge-0 indices
        int iA = csr[o0];
        int iB = csr[min(o0 + ha, lastE)];
        // edge-0 rows
        const uint4* pa = (const uint4*)(xbp + (size_t)iA * 64 + c * 16);
        uint4 ra0 = pa[0], ra1 = pa[1];
        const uint4* pb = (const uint4*)(xbp + (size_t)iB * 64 + c * 16);
        uint4 rb0 = pb[0], rb1 = pb[1];
        // edge-1 indices
        int iA1 = csr[min(o0 + 1, lastA)];
        int iB1 = csr[min(o0 + ha + 1, lastE)];
        for (int j = 0; j < ha; ++j) {
          // issue next rows (edge j+1)
          const uint4* na = (const uint4*)(xbp + (size_t)iA1 * 64 + c * 16);
          uint4 qa0 = na[0], qa1 = na[1];
          const uint4* nb = (const uint4*)(xbp + (size_t)iB1 * 64 + c * 16);
          uint4 qb0 = nb[0], qb1 = nb[1];
          // issue next-next indices (edge j+2)
          iA1 = csr[min(o0 + j + 2, lastA)];
          iB1 = csr[min(o0 + ha + j + 2, lastE)];
          // accumulate current rows
#define ACC2(dst_, u, k0)                                       \
          { unsigned int uu = (u);                              \
            dst_[k0]     += __uint_as_float(uu << 16);          \
            dst_[k0 + 1] += __uint_as_float(uu & 0xFFFF0000u); }
          ACC2(s, ra0.x, 0)  ACC2(s, ra0.y, 2)  ACC2(s, ra0.z, 4)  ACC2(s, ra0.w, 6)
          ACC2(s, ra1.x, 8)  ACC2(s, ra1.y, 10) ACC2(s, ra1.z, 12) ACC2(s, ra1.w, 14)
          if (j < hb) {
            ACC2(sb, rb0.x, 0)  ACC2(sb, rb0.y, 2)  ACC2(sb, rb0.z, 4)  ACC2(sb, rb0.w, 6)
            ACC2(sb, rb1.x, 8)  ACC2(sb, rb1.y, 10) ACC2(sb, rb1.z, 12) ACC2(sb, rb1.w, 14)
          }
#undef ACC2
          ra0 = qa0; ra1 = qa1; rb0 = qb0; rb1 = qb1;
        }
      }
    }
    const float inv = 1.0f / fmaxf((float)dg, 1.0f);
    unsigned int pk[8];
#pragma unroll
    for (int q = 0; q < 8; ++q)
      pk[q] = (unsigned int)f2bf((s[2 * q] + sb[2 * q]) * inv) |
              ((unsigned int)f2bf((s[2 * q + 1] + sb[2 * q + 1]) * inv) << 16);
    uint4 w0 = {pk[0], pk[1], pk[2], pk[3]};
    uint4 w1 = {pk[4], pk[5], pk[6], pk[7]};
    *(uint4*)(&Mt[nd * XT_S + c * 16]) = w0;
    *(uint4*)(&Mt[nd * XT_S + c * 16 + 8]) = w1;
  }

  // Wave-private handoff: ensure this wave's Mt writes complete before its
  // own cross-lane Mt reads. Compiler-only barrier + LDS drain (no s_barrier).
  __builtin_amdgcn_wave_barrier();
  asm volatile("s_waitcnt lgkmcnt(0)" ::: "memory");
  __builtin_amdgcn_wave_barrier();

  // ---- MFMA phase: wave w computes rows w*16..+15 x all 64 cols ----
  const int lane = tid & 63;
  const int w = tid >> 6;
  const int quad = lane >> 4;
  const int m = lane & 15;
  const int arow = (w << 4) + m;
  const int anode = tile0 + arow;

  bf16x8 aX0 = {}, aX1 = {};
  if (anode < n) {
    aX0 = *(const bf16x8*)(xb + (size_t)anode * 64 + quad * 8);
    aX1 = *(const bf16x8*)(xb + (size_t)anode * 64 + 32 + quad * 8);
  }
  bf16x8 aM0 = *(const bf16x8*)(&Mt[arow * XT_S + quad * 8]);
  bf16x8 aM1 = *(const bf16x8*)(&Mt[arow * XT_S + 32 + quad * 8]);

  f32x4 accu[4], accv[4];
#pragma unroll
  for (int nt = 0; nt < 4; ++nt) {
    const int nc = nt * 16 + m;
    // B-fragments straight from global (L1-resident: 24 KB total, shared by
    // all 4 waves of the block and all blocks on the CU)
    bf16x8 b0 = *(const bf16x8*)(WfcT_g + nc * 128 + quad * 8);
    bf16x8 b1 = *(const bf16x8*)(WfcT_g + nc * 128 + 32 + quad * 8);
    bf16x8 b2 = *(const bf16x8*)(WfcT_g + nc * 128 + 64 + quad * 8);
    bf16x8 b3 = *(const bf16x8*)(WfcT_g + nc * 128 + 96 + quad * 8);
    f32x4 acc = {0.f, 0.f, 0.f, 0.f};
    acc = __builtin_amdgcn_mfma_f32_16x16x32_bf16(aX0, b0, acc, 0, 0, 0);
    acc = __builtin_amdgcn_mfma_f32_16x16x32_bf16(aX1, b1, acc, 0, 0, 0);
    acc = __builtin_amdgcn_mfma_f32_16x16x32_bf16(aM0, b2, acc, 0, 0, 0);
    acc = __builtin_amdgcn_mfma_f32_16x16x32_bf16(aM1, b3, acc, 0, 0, 0);
    accu[nt] = acc;
    bf16x8 c0 = *(const bf16x8*)(WresT_g + nc * 64 + quad * 8);
    bf16x8 c1 = *(const bf16x8*)(WresT_g + nc * 64 + 32 + quad * 8);
    f32x4 accr = {0.f, 0.f, 0.f, 0.f};
    accr = __builtin_amdgcn_mfma_f32_16x16x32_bf16(aX0, c0, accr, 0, 0, 0);
    accr = __builtin_amdgcn_mfma_f32_16x16x32_bf16(aX1, c1, accr, 0, 0, 0);
    accv[nt] = accr;
  }

  // ---- epilogue: C/D layout col=lane&15, row=quad*4+reg ----
#pragma unroll
  for (int nt = 0; nt < 4; ++nt) {
    const int nc = nt * 16 + m;
    const float bf = b_fc[nc];
    const float br = b_res[nc];
#pragma unroll
    for (int r = 0; r < 4; ++r) {
      int lr = (w << 4) + (quad << 2) + r;
      int node = tile0 + lr;
      if (node < n) {
        float u = fmaxf(accu[nt][r] + bf, 0.f);
        out[node * 64 + nc] = u + accv[nt][r] + br;
      }
    }
  }
}

extern "C" void kernel_launch(void* const* d_in, const int* in_sizes, int n_in,
                              void* d_out, int out_size, void* d_ws, size_t ws_size,
                              hipStream_t stream) {
  const float* x = (const float*)d_in[0];
  const int* src = (const int*)d_in[1];
  const int* dst = (const int*)d_in[2];
  const float* W_fc = (const float*)d_in[3];
  const float* b_fc = (const float*)d_in[4];
  const float* W_res = (const float*)d_in[5];
  const float* b_res = (const float*)d_in[6];
  float* out = (float*)d_out;
  const int n = in_sizes[0] / 64;
  const int e = in_sizes[1];

  // workspace layout (~20 MB); 16B-aligned vector regions first
  char* p = (char*)d_ws;
  unsigned short* xb = (unsigned short*)p;      p += (size_t)n * 64 * 2;
  unsigned short* WfcT_g = (unsigned short*)p;  p += 64 * 128 * 2;
  unsigned short* WresT_g = (unsigned short*)p; p += 64 * 64 * 2;
  int* deg = (int*)p;                           p += (size_t)n * 4;
  int* offsets = (int*)p;                       p += (size_t)(n + 1) * 4;
  p = (char*)(((uintptr_t)p + 15) & ~(uintptr_t)15);
  int* blksum = (int*)p;                        p += 4096;
  int* rank = (int*)p;                          p += (size_t)e * 4;
  int* csr = (int*)p;

  hipMemsetAsync(deg, 0, (size_t)n * 4, stream);

  const int total4 = in_sizes[0] / 4;
  const int prep_n = (total4 > e) ? total4 : e;
  k_prep<<<(prep_n + 255) / 256, 256, 0, stream>>>(x, xb, total4, dst, deg, rank,
                                                   e, W_fc, WfcT_g, W_res, WresT_g);
  const int nblk = (n + 255) / 256;
  k_scan1<<<nblk, 256, 0, stream>>>(deg, offsets, blksum, n);
  k_scan2b<<<nblk, 256, 0, stream>>>(offsets, blksum, n, e);
  k_fill<<<(e / 4 + 255) / 256, 256, 0, stream>>>(src, dst, offsets, rank, csr, e);
  k_main<<<(n + 63) / 64, 256, 0, stream>>>(xb, offsets, csr, WfcT_g, WresT_g,
                                            b_fc, b_res, out, n);
}

// Round 3
// 177.848 us; speedup vs baseline: 1.0192x; 1.0192x over previous
//
#include <hip/hip_runtime.h>
#include <hip/hip_bf16.h>
#include <stdint.h>

// GraphSAGE layer fused pipeline for MI355X (gfx950), round 6.
// memset(deg+flags) | k_prep(cvt+hist+rank+Wcvt) | k_scan(fused lookback) |
// k_fill | k_main
// R4: k_main barrier-free (Mt wave-private), weights from global, LDS 9.2KB.
// R5: __launch_bounds__(256,6); occupancy 30->44% but k_main flat at 45us ->
//     gather is throughput-limited (~2.3 TB/s random 128B), not wave-starved.
// R6: pipeline attack: fused single-dispatch scan (decoupled lookback),
//     nontemporal out stores (kill 25.6MB RFO), one fewer L2-flush barrier.

typedef __bf16 bf16x8 __attribute__((ext_vector_type(8)));
typedef float f32x4 __attribute__((ext_vector_type(4)));

#define SCAN_READY 0x40000000
#define SCAN_MASK  0x3FFFFFFF

__device__ __forceinline__ unsigned short f2bf(float f) {
  unsigned int u = __float_as_uint(f);
  u += 0x7FFFu + ((u >> 16) & 1u);   // RNE
  return (unsigned short)(u >> 16);
}

// ---- fused prep: x->bf16, degree histogram + per-edge rank, W^T -> bf16 ----
__global__ void k_prep(const float* __restrict__ x, unsigned short* __restrict__ xb,
                       int total4,
                       const int* __restrict__ dst, int* __restrict__ deg,
                       int* __restrict__ rank, int e,
                       const float* __restrict__ W_fc, unsigned short* __restrict__ WfcT_g,
                       const float* __restrict__ W_res, unsigned short* __restrict__ WresT_g) {
  int i = blockIdx.x * 256 + threadIdx.x;
  if (i < total4) {
    const float4 v = ((const float4*)x)[i];
    ushort4 o;
    o.x = f2bf(v.x); o.y = f2bf(v.y); o.z = f2bf(v.z); o.w = f2bf(v.w);
    ((ushort4*)xb)[i] = o;
  }
  if (i < e) rank[i] = atomicAdd(&deg[dst[i]], 1);
  if (i < 64 * 128) {              // WfcT_g[nc*128+k] = W_fc[k*64+nc]
    int nc = i >> 7, k = i & 127;
    WfcT_g[i] = f2bf(W_fc[k * 64 + nc]);
  }
  if (i < 64 * 64) {               // WresT_g[nc*64+k] = W_res[k*64+nc]
    int nc = i >> 6, k = i & 63;
    WresT_g[i] = f2bf(W_res[k * 64 + nc]);
  }
}

// ---- fused scan: per-block scan + single-word-publish decoupled lookback ----
// blkagg[b] = (block aggregate) | SCAN_READY, published via device-scope
// atomicExch. Value and flag share one word -> no separate fence needed.
// CP dispatches blocks in order; block b only polls j<b (dispatched earlier,
// resident or retired) -> no deadlock. nblk=391, fully resident anyway.
__global__ void k_scan(const int* __restrict__ deg, int* __restrict__ offsets,
                       int* __restrict__ blkagg, int n, int e) {
  __shared__ int sc[256];
  __shared__ int red[4];
  const int b = blockIdx.x, t = threadIdx.x;
  const int i = b * 256 + t;
  int d = (i < n) ? deg[i] : 0;
  sc[t] = d;
  __syncthreads();
  for (int off = 1; off < 256; off <<= 1) {
    int v = (t >= off) ? sc[t - off] : 0;
    __syncthreads();
    sc[t] += v;
    __syncthreads();
  }
  if (t == 255) atomicExch(&blkagg[b], sc[255] | SCAN_READY);
  // lookback: sum all predecessor aggregates (poll until published)
  int v = 0;
  for (int j = t; j < b; j += 256) {
    int a;
    do {
      a = __hip_atomic_load(&blkagg[j], __ATOMIC_RELAXED, __HIP_MEMORY_SCOPE_AGENT);
    } while (!(a & SCAN_READY));
    v += a & SCAN_MASK;
  }
  v += __shfl_xor(v, 32); v += __shfl_xor(v, 16); v += __shfl_xor(v, 8);
  v += __shfl_xor(v, 4);  v += __shfl_xor(v, 2);  v += __shfl_xor(v, 1);
  if ((t & 63) == 0) red[t >> 6] = v;
  __syncthreads();
  const int pre = red[0] + red[1] + red[2] + red[3];
  if (i < n) offsets[i] = pre + sc[t] - d;
  if (b == (int)gridDim.x - 1 && t == 255) offsets[n] = e;
}

// ---- CSR fill: atomic-free, 4 edges per thread for ILP ----
__global__ void k_fill(const int* __restrict__ src, const int* __restrict__ dst,
                       const int* __restrict__ offsets, const int* __restrict__ rank,
                       int* __restrict__ csr, int e) {
  int i4 = (blockIdx.x * 256 + threadIdx.x) * 4;
  if (i4 + 3 < e) {
    const int4 d = *(const int4*)(dst + i4);
    const int4 r = *(const int4*)(rank + i4);
    const int4 s = *(const int4*)(src + i4);
    int p0 = offsets[d.x], p1 = offsets[d.y], p2 = offsets[d.z], p3 = offsets[d.w];
    csr[p0 + r.x] = s.x;
    csr[p1 + r.y] = s.y;
    csr[p2 + r.z] = s.z;
    csr[p3 + r.w] = s.w;
  } else {
    for (int i = i4; i < e; ++i) csr[offsets[dst[i]] + rank[i]] = src[i];
  }
}

// ---- fused main: 64-node tile per block, 4 waves, NO block barrier ----
// Mt rows for wave w's MFMA A-fragments (rows 16w..16w+15) are written
// exclusively by wave w's own gather threads (nd = tid>>2), so the
// gather->MFMA handoff is wave-private: no __syncthreads needed.
#define XT_S 72

__global__ __launch_bounds__(256, 6) void k_main(
    const unsigned short* __restrict__ xb,
    const int* __restrict__ offsets, const int* __restrict__ csr,
    const unsigned short* __restrict__ WfcT_g,
    const unsigned short* __restrict__ WresT_g,
    const float* __restrict__ b_fc, const float* __restrict__ b_res,
    float* __restrict__ out, int n) {
  __shared__ unsigned short Mt[64 * XT_S];     // mean tile, bf16 (9.2 KB)

  const int tid = threadIdx.x;
  const int tile0 = blockIdx.x * 64;

  // ---- gather: thread -> (node nd, 16-feature chunk c); two independent
  // edge chains per thread, each with dist-1 row / dist-2 index prefetch.
  {
    const int nd = tid >> 2;
    const int c = tid & 3;
    const int node = tile0 + nd;
    float s[16], sb[16];
#pragma unroll
    for (int k = 0; k < 16; ++k) { s[k] = 0.f; sb[k] = 0.f; }
    int dg = 0;
    if (node < n) {
      const int o0 = offsets[node];
      const int o1 = offsets[node + 1];
      dg = o1 - o0;
      if (dg > 0) {
        const int hb = dg >> 1;          // chain B length
        const int ha = dg - hb;          // chain A length (>= hb)
        const int lastA = o0 + ha - 1;
        const int lastE = o1 - 1;
        const unsigned short* __restrict__ xbp = xb;
        // edge-0 indices
        int iA = csr[o0];
        int iB = csr[min(o0 + ha, lastE)];
        // edge-0 rows
        const uint4* pa = (const uint4*)(xbp + (size_t)iA * 64 + c * 16);
        uint4 ra0 = pa[0], ra1 = pa[1];
        const uint4* pb = (const uint4*)(xbp + (size_t)iB * 64 + c * 16);
        uint4 rb0 = pb[0], rb1 = pb[1];
        // edge-1 indices
        int iA1 = csr[min(o0 + 1, lastA)];
        int iB1 = csr[min(o0 + ha + 1, lastE)];
        for (int j = 0; j < ha; ++j) {
          // issue next rows (edge j+1)
          const uint4* na = (const uint4*)(xbp + (size_t)iA1 * 64 + c * 16);
          uint4 qa0 = na[0], qa1 = na[1];
          const uint4* nb = (const uint4*)(xbp + (size_t)iB1 * 64 + c * 16);
          uint4 qb0 = nb[0], qb1 = nb[1];
          // issue next-next indices (edge j+2)
          iA1 = csr[min(o0 + j + 2, lastA)];
          iB1 = csr[min(o0 + ha + j + 2, lastE)];
          // accumulate current rows
#define ACC2(dst_, u, k0)                                       \
          { unsigned int uu = (u);                              \
            dst_[k0]     += __uint_as_float(uu << 16);          \
            dst_[k0 + 1] += __uint_as_float(uu & 0xFFFF0000u); }
          ACC2(s, ra0.x, 0)  ACC2(s, ra0.y, 2)  ACC2(s, ra0.z, 4)  ACC2(s, ra0.w, 6)
          ACC2(s, ra1.x, 8)  ACC2(s, ra1.y, 10) ACC2(s, ra1.z, 12) ACC2(s, ra1.w, 14)
          if (j < hb) {
            ACC2(sb, rb0.x, 0)  ACC2(sb, rb0.y, 2)  ACC2(sb, rb0.z, 4)  ACC2(sb, rb0.w, 6)
            ACC2(sb, rb1.x, 8)  ACC2(sb, rb1.y, 10) ACC2(sb, rb1.z, 12) ACC2(sb, rb1.w, 14)
          }
#undef ACC2
          ra0 = qa0; ra1 = qa1; rb0 = qb0; rb1 = qb1;
        }
      }
    }
    const float inv = 1.0f / fmaxf((float)dg, 1.0f);
    unsigned int pk[8];
#pragma unroll
    for (int q = 0; q < 8; ++q)
      pk[q] = (unsigned int)f2bf((s[2 * q] + sb[2 * q]) * inv) |
              ((unsigned int)f2bf((s[2 * q + 1] + sb[2 * q + 1]) * inv) << 16);
    uint4 w0 = {pk[0], pk[1], pk[2], pk[3]};
    uint4 w1 = {pk[4], pk[5], pk[6], pk[7]};
    *(uint4*)(&Mt[nd * XT_S + c * 16]) = w0;
    *(uint4*)(&Mt[nd * XT_S + c * 16 + 8]) = w1;
  }

  // Wave-private handoff: ensure this wave's Mt writes complete before its
  // own cross-lane Mt reads. Compiler-only barrier + LDS drain (no s_barrier).
  __builtin_amdgcn_wave_barrier();
  asm volatile("s_waitcnt lgkmcnt(0)" ::: "memory");
  __builtin_amdgcn_wave_barrier();

  // ---- MFMA phase: wave w computes rows w*16..+15 x all 64 cols ----
  const int lane = tid & 63;
  const int w = tid >> 6;
  const int quad = lane >> 4;
  const int m = lane & 15;
  const int arow = (w << 4) + m;
  const int anode = tile0 + arow;

  bf16x8 aX0 = {}, aX1 = {};
  if (anode < n) {
    aX0 = *(const bf16x8*)(xb + (size_t)anode * 64 + quad * 8);
    aX1 = *(const bf16x8*)(xb + (size_t)anode * 64 + 32 + quad * 8);
  }
  bf16x8 aM0 = *(const bf16x8*)(&Mt[arow * XT_S + quad * 8]);
  bf16x8 aM1 = *(const bf16x8*)(&Mt[arow * XT_S + 32 + quad * 8]);

  f32x4 accu[4], accv[4];
#pragma unroll
  for (int nt = 0; nt < 4; ++nt) {
    const int nc = nt * 16 + m;
    // B-fragments straight from global (L1-resident: 24 KB total, shared by
    // all 4 waves of the block and all blocks on the CU)
    bf16x8 b0 = *(const bf16x8*)(WfcT_g + nc * 128 + quad * 8);
    bf16x8 b1 = *(const bf16x8*)(WfcT_g + nc * 128 + 32 + quad * 8);
    bf16x8 b2 = *(const bf16x8*)(WfcT_g + nc * 128 + 64 + quad * 8);
    bf16x8 b3 = *(const bf16x8*)(WfcT_g + nc * 128 + 96 + quad * 8);
    f32x4 acc = {0.f, 0.f, 0.f, 0.f};
    acc = __builtin_amdgcn_mfma_f32_16x16x32_bf16(aX0, b0, acc, 0, 0, 0);
    acc = __builtin_amdgcn_mfma_f32_16x16x32_bf16(aX1, b1, acc, 0, 0, 0);
    acc = __builtin_amdgcn_mfma_f32_16x16x32_bf16(aM0, b2, acc, 0, 0, 0);
    acc = __builtin_amdgcn_mfma_f32_16x16x32_bf16(aM1, b3, acc, 0, 0, 0);
    accu[nt] = acc;
    bf16x8 c0 = *(const bf16x8*)(WresT_g + nc * 64 + quad * 8);
    bf16x8 c1 = *(const bf16x8*)(WresT_g + nc * 64 + 32 + quad * 8);
    f32x4 accr = {0.f, 0.f, 0.f, 0.f};
    accr = __builtin_amdgcn_mfma_f32_16x16x32_bf16(aX0, c0, accr, 0, 0, 0);
    accr = __builtin_amdgcn_mfma_f32_16x16x32_bf16(aX1, c1, accr, 0, 0, 0);
    accv[nt] = accr;
  }

  // ---- epilogue: C/D layout col=lane&15, row=quad*4+reg ----
  // Nontemporal stores: out is write-once, never re-read by us -> avoid
  // 25.6MB write-allocate RFO fetch (R2 counters: FETCH 46MB ~ 25MB was RFO).
#pragma unroll
  for (int nt = 0; nt < 4; ++nt) {
    const int nc = nt * 16 + m;
    const float bf = b_fc[nc];
    const float br = b_res[nc];
#pragma unroll
    for (int r = 0; r < 4; ++r) {
      int lr = (w << 4) + (quad << 2) + r;
      int node = tile0 + lr;
      if (node < n) {
        float u = fmaxf(accu[nt][r] + bf, 0.f);
        __builtin_nontemporal_store(u + accv[nt][r] + br, &out[node * 64 + nc]);
      }
    }
  }
}

extern "C" void kernel_launch(void* const* d_in, const int* in_sizes, int n_in,
                              void* d_out, int out_size, void* d_ws, size_t ws_size,
                              hipStream_t stream) {
  const float* x = (const float*)d_in[0];
  const int* src = (const int*)d_in[1];
  const int* dst = (const int*)d_in[2];
  const float* W_fc = (const float*)d_in[3];
  const float* b_fc = (const float*)d_in[4];
  const float* W_res = (const float*)d_in[5];
  const float* b_res = (const float*)d_in[6];
  float* out = (float*)d_out;
  const int n = in_sizes[0] / 64;
  const int e = in_sizes[1];

  // workspace layout (~20 MB); 16B-aligned vector regions first
  char* p = (char*)d_ws;
  unsigned short* xb = (unsigned short*)p;      p += (size_t)n * 64 * 2;
  unsigned short* WfcT_g = (unsigned short*)p;  p += 64 * 128 * 2;
  unsigned short* WresT_g = (unsigned short*)p; p += 64 * 64 * 2;
  int* deg = (int*)p;                           p += (size_t)n * 4;
  int* blkagg = (int*)p;                        p += 4096;       // scan flags, zeroed with deg
  int* offsets = (int*)p;                       p += (size_t)(n + 1) * 4;
  p = (char*)(((uintptr_t)p + 15) & ~(uintptr_t)15);
  int* rank = (int*)p;                          p += (size_t)e * 4;
  int* csr = (int*)p;

  // one memset covers deg + blkagg (contiguous; workspace is re-poisoned
  // every iteration so the scan flags MUST be zeroed here)
  hipMemsetAsync(deg, 0, (size_t)n * 4 + 4096, stream);

  const int total4 = in_sizes[0] / 4;
  const int prep_n = (total4 > e) ? total4 : e;
  k_prep<<<(prep_n + 255) / 256, 256, 0, stream>>>(x, xb, total4, dst, deg, rank,
                                                   e, W_fc, WfcT_g, W_res, WresT_g);
  const int nblk = (n + 255) / 256;
  k_scan<<<nblk, 256, 0, stream>>>(deg, offsets, blkagg, n, e);
  k_fill<<<(e / 4 + 255) / 256, 256, 0, stream>>>(src, dst, offsets, rank, csr, e);
  k_main<<<(n + 63) / 64, 256, 0, stream>>>(xb, offsets, csr, WfcT_g, WresT_g,
                                            b_fc, b_res, out, n);
}